// Round 2
// baseline (10760.943 us; speedup 1.0000x reference)
//
#include <hip/hip_runtime.h>
#include <cstddef>

constexpr int kB = 2;
constexpr int kN = 16384;
constexpr int kC = 64;
constexpr int kS = 4096;   // NPOINT
constexpr int kNS = 32;    // NSAMPLE

typedef float f32x2 __attribute__((ext_vector_type(2)));

// -------- transpose [b][Cdim][Ndim] -> [b][Ndim][Cdim], 32x32 tiles --------
__global__ void transpose_kernel(const float* __restrict__ in,
                                 float* __restrict__ out,
                                 int Cdim, int Ndim) {
  __shared__ float tile[32][33];
  int b = blockIdx.z;
  int n0 = blockIdx.x * 32;
  int c0 = blockIdx.y * 32;
  int tx = threadIdx.x;
  const float* inb = in + (size_t)b * Cdim * Ndim;
  float* outb = out + (size_t)b * Cdim * Ndim;
#pragma unroll
  for (int i = threadIdx.y; i < 32; i += 8)
    tile[i][tx] = inb[(size_t)(c0 + i) * Ndim + (n0 + tx)];
  __syncthreads();
#pragma unroll
  for (int i = threadIdx.y; i < 32; i += 8)
    outb[(size_t)(n0 + i) * Cdim + (c0 + tx)] = tile[tx][i];
}

// -------- farthest point sampling v2 --------
// 512 threads/block, one block per batch. Each thread owns 32 points as 16
// float2 pairs: pair m holds points p0 = m*1024 + t, p1 = m*1024 + 512 + t.
// Distance math uses v_pk_add/mul_f32 (IEEE RNE per half == numpy rounding).
// Reduction: per-thread (bestv,besti) -> LDS (double-buffered), ONE barrier,
// every wave redundantly reduces all 512 partials (deterministic, identical).
__global__ __launch_bounds__(512, 2) void fps_kernel(const float* __restrict__ xyz,
                                                     float* __restrict__ new_xyz) {
  const int b = blockIdx.x;
  const int t = threadIdx.x;
  const int lane = t & 63;
  const float* P = xyz + (size_t)b * kN * 3;

  f32x2 px[16], py[16], pz[16], dist[16];
#pragma unroll
  for (int m = 0; m < 16; m++) {
    int p0 = m * 1024 + t;
    int p1 = p0 + 512;
    px[m] = f32x2{P[p0 * 3 + 0], P[p1 * 3 + 0]};
    py[m] = f32x2{P[p0 * 3 + 1], P[p1 * 3 + 1]};
    pz[m] = f32x2{P[p0 * 3 + 2], P[p1 * 3 + 2]};
    dist[m] = f32x2{1e10f, 1e10f};
  }

  __shared__ f32x2 red[2][512];

  float cx = P[0], cy = P[1], cz = P[2];

  for (int i = 0; i < kS; i++) {
    if (t == 0) {
      float* o = new_xyz + ((size_t)b * kS + i) * 3;
      o[0] = cx; o[1] = cy; o[2] = cz;
    }
    const f32x2 ncx = f32x2{-cx, -cx};
    const f32x2 ncy = f32x2{-cy, -cy};
    const f32x2 ncz = f32x2{-cz, -cz};

    float bestv = -1.0f;
    int besti = 0x7fffffff;
#pragma unroll
    for (int m = 0; m < 16; m++) {
      f32x2 dx, dy, dz, xx, yy, zz, s1, d2;
      asm("v_pk_add_f32 %0, %1, %2" : "=v"(dx) : "v"(px[m]), "v"(ncx));
      asm("v_pk_add_f32 %0, %1, %2" : "=v"(dy) : "v"(py[m]), "v"(ncy));
      asm("v_pk_add_f32 %0, %1, %2" : "=v"(dz) : "v"(pz[m]), "v"(ncz));
      asm("v_pk_mul_f32 %0, %1, %1" : "=v"(xx) : "v"(dx));
      asm("v_pk_mul_f32 %0, %1, %1" : "=v"(yy) : "v"(dy));
      asm("v_pk_mul_f32 %0, %1, %1" : "=v"(zz) : "v"(dz));
      asm("v_pk_add_f32 %0, %1, %2" : "=v"(s1) : "v"(xx), "v"(yy));
      asm("v_pk_add_f32 %0, %1, %2" : "=v"(d2) : "v"(s1), "v"(zz));
      float dk0 = fminf(dist[m].x, d2.x);
      float dk1 = fminf(dist[m].y, d2.y);
      dist[m].x = dk0;
      dist[m].y = dk1;
      if (dk0 > bestv) { bestv = dk0; besti = m * 1024 + t; }
      if (dk1 > bestv) { bestv = dk1; besti = m * 1024 + 512 + t; }
    }

    red[i & 1][t] = f32x2{bestv, __int_as_float(besti)};
    __syncthreads();

    float bv = -1.0f;
    int bi = 0x7fffffff;
#pragma unroll
    for (int j = 0; j < 8; j++) {
      f32x2 pr = red[i & 1][j * 64 + lane];
      float v = pr.x;
      int ix = __float_as_int(pr.y);
      if (v > bv || (v == bv && ix < bi)) { bv = v; bi = ix; }
    }
#pragma unroll
    for (int off = 32; off >= 1; off >>= 1) {
      float ov = __shfl_xor(bv, off, 64);
      int oi = __shfl_xor(bi, off, 64);
      if (ov > bv || (ov == bv && oi < bi)) { bv = ov; bi = oi; }
    }
    int far = __builtin_amdgcn_readfirstlane(bi);
    cx = P[far * 3 + 0];
    cy = P[far * 3 + 1];
    cz = P[far * 3 + 2];
  }
}

// -------- ball query: one wave per query, first-32 ascending indices --------
__global__ __launch_bounds__(256) void ball_query_kernel(const float* __restrict__ xyz,
                                                         const float* __restrict__ new_xyz,
                                                         int* __restrict__ idx) {
  const int q = (int)((blockIdx.x * 256 + threadIdx.x) >> 6);
  const int lane = threadIdx.x & 63;
  const int b = q >> 12;
  const float* P = xyz + (size_t)b * kN * 3;
  const float qx = new_xyz[q * 3 + 0];
  const float qy = new_xyz[q * 3 + 1];
  const float qz = new_xyz[q * 3 + 2];
  int cnt = 0;
  int first = -1;
  const int base = q * kNS;
  for (int j = 0; j < kN / 64; j++) {
    const int p = (j << 6) + lane;
    float dx = P[p * 3 + 0] - qx;
    float dy = P[p * 3 + 1] - qy;
    float dz = P[p * 3 + 2] - qz;
    float d = __fadd_rn(__fadd_rn(__fmul_rn(dx, dx), __fmul_rn(dy, dy)),
                        __fmul_rn(dz, dz));
    bool inb = d < 0.25f;
    unsigned long long m = __ballot(inb);
    if (first < 0 && m != 0ull) first = (j << 6) + (__ffsll(m) - 1);
    if (inb && cnt < kNS) {
      int r = cnt + (int)__popcll(m & ((1ull << lane) - 1ull));
      if (r < kNS) idx[base + r] = p;
    }
    cnt += (int)__popcll(m);
    if (cnt >= kNS) break;
  }
  if (cnt < kNS) {
    int fill = (first >= 0) ? first : 0;
    if (lane >= cnt && lane < kNS) idx[base + lane] = fill;
  }
}

// -------- gather + MLP(67->64->64->128) + maxpool + agg(128->128) + score ----
__global__ __launch_bounds__(128) void group_mlp_kernel(
    const float* __restrict__ xyz, const float* __restrict__ new_xyz,
    const float* __restrict__ featsT, const int* __restrict__ nidx,
    const float* __restrict__ w1, const float* __restrict__ b1,
    const float* __restrict__ w2, const float* __restrict__ b2,
    const float* __restrict__ w3, const float* __restrict__ b3,
    const float* __restrict__ wa, const float* __restrict__ ba,
    const float* __restrict__ wc, const float* __restrict__ bc,
    float* __restrict__ aggT, float* __restrict__ scores) {
  __shared__ float smem[2 * 4384];
  const int wid = threadIdx.x >> 6;
  const int lane = threadIdx.x & 63;
  const int q = blockIdx.x * 2 + wid;
  const int b = q >> 12;
  float* Xs = smem + wid * 4384;   // [32][68] input; later reused as H2 [32][64]
  float* H1 = Xs + 32 * 68;        // [32][64]
  float* pool = H1 + 32 * 64;      // [128]
  int* idxs = (int*)(pool + 128);  // [32]

  if (lane < 32) idxs[lane] = nidx[q * kNS + lane];
  const float qx = new_xyz[q * 3 + 0];
  const float qy = new_xyz[q * 3 + 1];
  const float qz = new_xyz[q * 3 + 2];
  __syncthreads();

  const float* P = xyz + (size_t)b * kN * 3;
  const float* F = featsT + (size_t)b * kN * kC;
  if (lane < 32) {
    int p = idxs[lane];
    Xs[lane * 68 + 0] = P[p * 3 + 0] - qx;
    Xs[lane * 68 + 1] = P[p * 3 + 1] - qy;
    Xs[lane * 68 + 2] = P[p * 3 + 2] - qz;
  } else {
    Xs[(lane - 32) * 68 + 67] = 0.0f;   // pad column
  }
  for (int j = 0; j < 32; j++) {
    Xs[j * 68 + 3 + lane] = F[(size_t)idxs[j] * kC + lane];
  }
  __syncthreads();

  float w[68];
  // ---- layer 1: 67 -> 64, lane = out channel ----
  {
    const int o = lane;
#pragma unroll
    for (int k = 0; k < 67; k++) w[k] = w1[o * 67 + k];
    w[67] = 0.0f;
    const float bias = b1[o];
    for (int r = 0; r < 32; r++) {
      float acc = bias;
#pragma unroll
      for (int k4 = 0; k4 < 17; k4++) {
        float4 x = *(const float4*)&Xs[r * 68 + k4 * 4];
        acc += x.x * w[k4 * 4 + 0] + x.y * w[k4 * 4 + 1] +
               x.z * w[k4 * 4 + 2] + x.w * w[k4 * 4 + 3];
      }
      H1[r * 64 + o] = fmaxf(acc, 0.0f);
    }
  }
  __syncthreads();
  // ---- layer 2: 64 -> 64, write H2 into Xs region ----
  {
    const int o = lane;
#pragma unroll
    for (int k = 0; k < 64; k++) w[k] = w2[o * 64 + k];
    const float bias = b2[o];
    for (int r = 0; r < 32; r++) {
      float acc = bias;
#pragma unroll
      for (int k4 = 0; k4 < 16; k4++) {
        float4 x = *(const float4*)&H1[r * 64 + k4 * 4];
        acc += x.x * w[k4 * 4 + 0] + x.y * w[k4 * 4 + 1] +
               x.z * w[k4 * 4 + 2] + x.w * w[k4 * 4 + 3];
      }
      Xs[r * 64 + o] = fmaxf(acc, 0.0f);
    }
  }
  __syncthreads();
  // ---- layer 3: 64 -> 128 (2 out channels per lane) + maxpool over rows ----
  {
    const int c = lane;
    float wB[64];
#pragma unroll
    for (int k = 0; k < 64; k++) {
      w[k] = w3[c * 64 + k];
      wB[k] = w3[(c + 64) * 64 + k];
    }
    const float biasA = b3[c];
    const float biasB = b3[c + 64];
    float pa = 0.0f, pb = 0.0f;   // relu folded: max over relu(h) == max(0, max h)
    for (int r = 0; r < 32; r++) {
      float a = biasA, bb = biasB;
#pragma unroll
      for (int k4 = 0; k4 < 16; k4++) {
        float4 x = *(const float4*)&Xs[r * 64 + k4 * 4];
        a  += x.x * w[k4 * 4 + 0] + x.y * w[k4 * 4 + 1] +
              x.z * w[k4 * 4 + 2] + x.w * w[k4 * 4 + 3];
        bb += x.x * wB[k4 * 4 + 0] + x.y * wB[k4 * 4 + 1] +
              x.z * wB[k4 * 4 + 2] + x.w * wB[k4 * 4 + 3];
      }
      pa = fmaxf(pa, a);
      pb = fmaxf(pb, bb);
    }
    pool[c] = pa;
    pool[c + 64] = pb;
  }
  __syncthreads();
  // ---- aggregation 128->128 + relu, confidence 128->1 ----
  {
    const int c = lane;
    float accA = ba[c], accB = ba[c + 64];
#pragma unroll
    for (int k4 = 0; k4 < 32; k4++) {
      float4 pv = *(const float4*)&pool[k4 * 4];
      float4 wva = *(const float4*)&wa[c * 128 + k4 * 4];
      float4 wvb = *(const float4*)&wa[(c + 64) * 128 + k4 * 4];
      accA += pv.x * wva.x + pv.y * wva.y + pv.z * wva.z + pv.w * wva.w;
      accB += pv.x * wvb.x + pv.y * wvb.y + pv.z * wvb.z + pv.w * wvb.w;
    }
    float aggA = fmaxf(accA, 0.0f);
    float aggB = fmaxf(accB, 0.0f);
    aggT[(size_t)q * 128 + c] = aggA;
    aggT[(size_t)q * 128 + 64 + c] = aggB;
    float partial = aggA * wc[c] + aggB * wc[c + 64];
#pragma unroll
    for (int off = 32; off >= 1; off >>= 1) partial += __shfl_xor(partial, off, 64);
    if (lane == 0) scores[q] = partial + bc[0];
  }
}

extern "C" void kernel_launch(void* const* d_in, const int* in_sizes, int n_in,
                              void* d_out, int out_size, void* d_ws, size_t ws_size,
                              hipStream_t stream) {
  const float* xyz   = (const float*)d_in[0];
  const float* feats = (const float*)d_in[1];
  const float* w1 = (const float*)d_in[2];
  const float* b1 = (const float*)d_in[3];
  const float* w2 = (const float*)d_in[4];
  const float* b2 = (const float*)d_in[5];
  const float* w3 = (const float*)d_in[6];
  const float* b3 = (const float*)d_in[7];
  const float* wa = (const float*)d_in[8];
  const float* ba = (const float*)d_in[9];
  const float* wc = (const float*)d_in[10];
  const float* bc = (const float*)d_in[11];

  float* out_new_xyz = (float*)d_out;                               // B*S*3
  float* out_feat    = out_new_xyz + (size_t)kB * kS * 3;           // B*128*S
  float* out_scores  = out_feat + (size_t)kB * 128 * kS;            // B*S

  // workspace layout (bytes): featsT [0, 8MiB), idx [8MiB, 9MiB), aggT [9MiB, 13MiB)
  float* featsT = (float*)d_ws;
  int*   idxbuf = (int*)((char*)d_ws + (size_t)8 * 1024 * 1024);
  float* aggT   = (float*)((char*)d_ws + (size_t)9 * 1024 * 1024);

  // features (B,C,N) -> featsT (B,N,C)
  transpose_kernel<<<dim3(kN / 32, kC / 32, kB), dim3(32, 8, 1), 0, stream>>>(
      feats, featsT, kC, kN);
  // FPS -> new_xyz
  fps_kernel<<<dim3(kB), dim3(512), 0, stream>>>(xyz, out_new_xyz);
  // ball query -> idx
  ball_query_kernel<<<dim3(kB * kS / 4), dim3(256), 0, stream>>>(
      xyz, out_new_xyz, idxbuf);
  // gather + MLPs + pool + agg + scores
  group_mlp_kernel<<<dim3(kB * kS / 2), dim3(128), 0, stream>>>(
      xyz, out_new_xyz, featsT, idxbuf,
      w1, b1, w2, b2, w3, b3, wa, ba, wc, bc, aggT, out_scores);
  // aggT (B,S,128) -> new_features (B,128,S)
  transpose_kernel<<<dim3(128 / 32, kS / 32, kB), dim3(32, 8, 1), 0, stream>>>(
      aggT, out_feat, kS, 128);
}

// Round 3
// 9941.017 us; speedup vs baseline: 1.0825x; 1.0825x over previous
//
#include <hip/hip_runtime.h>
#include <cstddef>

constexpr int kB = 2;
constexpr int kN = 16384;
constexpr int kC = 64;
constexpr int kS = 4096;   // NPOINT
constexpr int kNS = 32;    // NSAMPLE

// -------- transpose [b][Cdim][Ndim] -> [b][Ndim][Cdim], 32x32 tiles --------
__global__ void transpose_kernel(const float* __restrict__ in,
                                 float* __restrict__ out,
                                 int Cdim, int Ndim) {
  __shared__ float tile[32][33];
  int b = blockIdx.z;
  int n0 = blockIdx.x * 32;
  int c0 = blockIdx.y * 32;
  int tx = threadIdx.x;
  const float* inb = in + (size_t)b * Cdim * Ndim;
  float* outb = out + (size_t)b * Cdim * Ndim;
#pragma unroll
  for (int i = threadIdx.y; i < 32; i += 8)
    tile[i][tx] = inb[(size_t)(c0 + i) * Ndim + (n0 + tx)];
  __syncthreads();
#pragma unroll
  for (int i = threadIdx.y; i < 32; i += 8)
    outb[(size_t)(n0 + i) * Cdim + (c0 + tx)] = tile[tx][i];
}

// -------- farthest point sampling v3 --------
// 1024 threads/block (16 waves = 4/SIMD = sole block on CU), one block/batch.
// __launch_bounds__(1024,4) -> VGPR budget 128: the 64 floats of per-thread
// state (px,py,pz,dist x16) live in REGISTERS (v1/v2 spilled them at VGPR<=104).
// Inner loop: 10 VALU/pt, exact numpy rounding (no FMA), value-only max.
// Index extracted afterwards via 16 v_cmp + per-wave ballot (scalar path).
// Centroid re-fetched through readfirstlane -> s_load (SGPR broadcast).
__global__ __launch_bounds__(1024, 4) void fps_kernel(const float* __restrict__ xyz,
                                                      float* __restrict__ new_xyz) {
  const int b = blockIdx.x;
  const int t = threadIdx.x;
  const int lane = t & 63;
  const int w = t >> 6;
  const float* P = xyz + (size_t)b * kN * 3;

  float px[16], py[16], pz[16], dist[16];
#pragma unroll
  for (int k = 0; k < 16; k++) {
    int p = (k << 10) + t;
    px[k] = P[p * 3 + 0];
    py[k] = P[p * 3 + 1];
    pz[k] = P[p * 3 + 2];
    dist[k] = 1e10f;
  }

  __shared__ float lds_v[16];
  __shared__ int lds_i[16];

  float cx = P[0], cy = P[1], cz = P[2];

  for (int i = 0; i < kS; i++) {
    if (t == 0) {
      float* o = new_xyz + ((size_t)b * kS + i) * 3;
      o[0] = cx; o[1] = cy; o[2] = cz;
    }
    float bestv = -1.0f;
#pragma unroll
    for (int k = 0; k < 16; k++) {
      float dx = cx - px[k];   // == -(px-cx); square is bit-identical
      float dy = cy - py[k];
      float dz = cz - pz[k];
      float d = __fadd_rn(__fadd_rn(__fmul_rn(dx, dx), __fmul_rn(dy, dy)),
                          __fmul_rn(dz, dz));
      float dk = fminf(dist[k], d);
      dist[k] = dk;
      bestv = fmaxf(bestv, dk);
    }
    // wave-level value max (6 shuffles)
#pragma unroll
    for (int off = 32; off >= 1; off >>= 1)
      bestv = fmaxf(bestv, __shfl_xor(bestv, off, 64));
    if (lane == 0) lds_v[w] = bestv;
    __syncthreads();
    // block max, uniform in every lane (4 shuffles over 16 partials)
    float bv = lds_v[lane & 15];
#pragma unroll
    for (int off = 8; off >= 1; off >>= 1)
      bv = fmaxf(bv, __shfl_xor(bv, off, 64));
    // per-wave min index matching bv (descending k: lowest k wins; ffs: lowest lane)
    int widx = 0x7fffffff;
#pragma unroll
    for (int k = 15; k >= 0; --k) {
      unsigned long long m = __ballot(dist[k] == bv);
      if (m != 0ull) widx = (k << 10) + (w << 6) + (__ffsll(m) - 1);
    }
    if (lane == 0) lds_i[w] = widx;
    __syncthreads();
    // block min index
    int vi = lds_i[lane & 15];
#pragma unroll
    for (int off = 8; off >= 1; off >>= 1)
      vi = min(vi, __shfl_xor(vi, off, 64));
    const int far = __builtin_amdgcn_readfirstlane(vi);
    cx = P[far * 3 + 0];
    cy = P[far * 3 + 1];
    cz = P[far * 3 + 2];
  }
}

// -------- ball query: one wave per query, first-32 ascending indices --------
__global__ __launch_bounds__(256) void ball_query_kernel(const float* __restrict__ xyz,
                                                         const float* __restrict__ new_xyz,
                                                         int* __restrict__ idx) {
  const int q = (int)((blockIdx.x * 256 + threadIdx.x) >> 6);
  const int lane = threadIdx.x & 63;
  const int b = q >> 12;
  const float* P = xyz + (size_t)b * kN * 3;
  const float qx = new_xyz[q * 3 + 0];
  const float qy = new_xyz[q * 3 + 1];
  const float qz = new_xyz[q * 3 + 2];
  int cnt = 0;
  int first = -1;
  const int base = q * kNS;
  for (int j = 0; j < kN / 64; j++) {
    const int p = (j << 6) + lane;
    float dx = P[p * 3 + 0] - qx;
    float dy = P[p * 3 + 1] - qy;
    float dz = P[p * 3 + 2] - qz;
    float d = __fadd_rn(__fadd_rn(__fmul_rn(dx, dx), __fmul_rn(dy, dy)),
                        __fmul_rn(dz, dz));
    bool inb = d < 0.25f;
    unsigned long long m = __ballot(inb);
    if (first < 0 && m != 0ull) first = (j << 6) + (__ffsll(m) - 1);
    if (inb && cnt < kNS) {
      int r = cnt + (int)__popcll(m & ((1ull << lane) - 1ull));
      if (r < kNS) idx[base + r] = p;
    }
    cnt += (int)__popcll(m);
    if (cnt >= kNS) break;
  }
  if (cnt < kNS) {
    int fill = (first >= 0) ? first : 0;
    if (lane >= cnt && lane < kNS) idx[base + lane] = fill;
  }
}

// -------- gather + MLP(67->64->64->128) + maxpool + agg(128->128) + score ----
__global__ __launch_bounds__(128) void group_mlp_kernel(
    const float* __restrict__ xyz, const float* __restrict__ new_xyz,
    const float* __restrict__ featsT, const int* __restrict__ nidx,
    const float* __restrict__ w1, const float* __restrict__ b1,
    const float* __restrict__ w2, const float* __restrict__ b2,
    const float* __restrict__ w3, const float* __restrict__ b3,
    const float* __restrict__ wa, const float* __restrict__ ba,
    const float* __restrict__ wc, const float* __restrict__ bc,
    float* __restrict__ aggT, float* __restrict__ scores) {
  __shared__ float smem[2 * 4384];
  const int wid = threadIdx.x >> 6;
  const int lane = threadIdx.x & 63;
  const int q = blockIdx.x * 2 + wid;
  const int b = q >> 12;
  float* Xs = smem + wid * 4384;   // [32][68] input; later reused as H2 [32][64]
  float* H1 = Xs + 32 * 68;        // [32][64]
  float* pool = H1 + 32 * 64;      // [128]
  int* idxs = (int*)(pool + 128);  // [32]

  if (lane < 32) idxs[lane] = nidx[q * kNS + lane];
  const float qx = new_xyz[q * 3 + 0];
  const float qy = new_xyz[q * 3 + 1];
  const float qz = new_xyz[q * 3 + 2];
  __syncthreads();

  const float* P = xyz + (size_t)b * kN * 3;
  const float* F = featsT + (size_t)b * kN * kC;
  if (lane < 32) {
    int p = idxs[lane];
    Xs[lane * 68 + 0] = P[p * 3 + 0] - qx;
    Xs[lane * 68 + 1] = P[p * 3 + 1] - qy;
    Xs[lane * 68 + 2] = P[p * 3 + 2] - qz;
  } else {
    Xs[(lane - 32) * 68 + 67] = 0.0f;   // pad column
  }
  for (int j = 0; j < 32; j++) {
    Xs[j * 68 + 3 + lane] = F[(size_t)idxs[j] * kC + lane];
  }
  __syncthreads();

  float w[68];
  // ---- layer 1: 67 -> 64, lane = out channel ----
  {
    const int o = lane;
#pragma unroll
    for (int k = 0; k < 67; k++) w[k] = w1[o * 67 + k];
    w[67] = 0.0f;
    const float bias = b1[o];
    for (int r = 0; r < 32; r++) {
      float acc = bias;
#pragma unroll
      for (int k4 = 0; k4 < 17; k4++) {
        float4 x = *(const float4*)&Xs[r * 68 + k4 * 4];
        acc += x.x * w[k4 * 4 + 0] + x.y * w[k4 * 4 + 1] +
               x.z * w[k4 * 4 + 2] + x.w * w[k4 * 4 + 3];
      }
      H1[r * 64 + o] = fmaxf(acc, 0.0f);
    }
  }
  __syncthreads();
  // ---- layer 2: 64 -> 64, write H2 into Xs region ----
  {
    const int o = lane;
#pragma unroll
    for (int k = 0; k < 64; k++) w[k] = w2[o * 64 + k];
    const float bias = b2[o];
    for (int r = 0; r < 32; r++) {
      float acc = bias;
#pragma unroll
      for (int k4 = 0; k4 < 16; k4++) {
        float4 x = *(const float4*)&H1[r * 64 + k4 * 4];
        acc += x.x * w[k4 * 4 + 0] + x.y * w[k4 * 4 + 1] +
               x.z * w[k4 * 4 + 2] + x.w * w[k4 * 4 + 3];
      }
      Xs[r * 64 + o] = fmaxf(acc, 0.0f);
    }
  }
  __syncthreads();
  // ---- layer 3: 64 -> 128 (2 out channels per lane) + maxpool over rows ----
  {
    const int c = lane;
    float wB[64];
#pragma unroll
    for (int k = 0; k < 64; k++) {
      w[k] = w3[c * 64 + k];
      wB[k] = w3[(c + 64) * 64 + k];
    }
    const float biasA = b3[c];
    const float biasB = b3[c + 64];
    float pa = 0.0f, pb = 0.0f;   // relu folded: max over relu(h) == max(0, max h)
    for (int r = 0; r < 32; r++) {
      float a = biasA, bb = biasB;
#pragma unroll
      for (int k4 = 0; k4 < 16; k4++) {
        float4 x = *(const float4*)&Xs[r * 64 + k4 * 4];
        a  += x.x * w[k4 * 4 + 0] + x.y * w[k4 * 4 + 1] +
              x.z * w[k4 * 4 + 2] + x.w * w[k4 * 4 + 3];
        bb += x.x * wB[k4 * 4 + 0] + x.y * wB[k4 * 4 + 1] +
              x.z * wB[k4 * 4 + 2] + x.w * wB[k4 * 4 + 3];
      }
      pa = fmaxf(pa, a);
      pb = fmaxf(pb, bb);
    }
    pool[c] = pa;
    pool[c + 64] = pb;
  }
  __syncthreads();
  // ---- aggregation 128->128 + relu, confidence 128->1 ----
  {
    const int c = lane;
    float accA = ba[c], accB = ba[c + 64];
#pragma unroll
    for (int k4 = 0; k4 < 32; k4++) {
      float4 pv = *(const float4*)&pool[k4 * 4];
      float4 wva = *(const float4*)&wa[c * 128 + k4 * 4];
      float4 wvb = *(const float4*)&wa[(c + 64) * 128 + k4 * 4];
      accA += pv.x * wva.x + pv.y * wva.y + pv.z * wva.z + pv.w * wva.w;
      accB += pv.x * wvb.x + pv.y * wvb.y + pv.z * wvb.z + pv.w * wvb.w;
    }
    float aggA = fmaxf(accA, 0.0f);
    float aggB = fmaxf(accB, 0.0f);
    aggT[(size_t)q * 128 + c] = aggA;
    aggT[(size_t)q * 128 + 64 + c] = aggB;
    float partial = aggA * wc[c] + aggB * wc[c + 64];
#pragma unroll
    for (int off = 32; off >= 1; off >>= 1) partial += __shfl_xor(partial, off, 64);
    if (lane == 0) scores[q] = partial + bc[0];
  }
}

extern "C" void kernel_launch(void* const* d_in, const int* in_sizes, int n_in,
                              void* d_out, int out_size, void* d_ws, size_t ws_size,
                              hipStream_t stream) {
  const float* xyz   = (const float*)d_in[0];
  const float* feats = (const float*)d_in[1];
  const float* w1 = (const float*)d_in[2];
  const float* b1 = (const float*)d_in[3];
  const float* w2 = (const float*)d_in[4];
  const float* b2 = (const float*)d_in[5];
  const float* w3 = (const float*)d_in[6];
  const float* b3 = (const float*)d_in[7];
  const float* wa = (const float*)d_in[8];
  const float* ba = (const float*)d_in[9];
  const float* wc = (const float*)d_in[10];
  const float* bc = (const float*)d_in[11];

  float* out_new_xyz = (float*)d_out;                               // B*S*3
  float* out_feat    = out_new_xyz + (size_t)kB * kS * 3;           // B*128*S
  float* out_scores  = out_feat + (size_t)kB * 128 * kS;            // B*S

  // workspace layout (bytes): featsT [0, 8MiB), idx [8MiB, 9MiB), aggT [9MiB, 13MiB)
  float* featsT = (float*)d_ws;
  int*   idxbuf = (int*)((char*)d_ws + (size_t)8 * 1024 * 1024);
  float* aggT   = (float*)((char*)d_ws + (size_t)9 * 1024 * 1024);

  // features (B,C,N) -> featsT (B,N,C)
  transpose_kernel<<<dim3(kN / 32, kC / 32, kB), dim3(32, 8, 1), 0, stream>>>(
      feats, featsT, kC, kN);
  // FPS -> new_xyz
  fps_kernel<<<dim3(kB), dim3(1024), 0, stream>>>(xyz, out_new_xyz);
  // ball query -> idx
  ball_query_kernel<<<dim3(kB * kS / 4), dim3(256), 0, stream>>>(
      xyz, out_new_xyz, idxbuf);
  // gather + MLPs + pool + agg + scores
  group_mlp_kernel<<<dim3(kB * kS / 2), dim3(128), 0, stream>>>(
      xyz, out_new_xyz, featsT, idxbuf,
      w1, b1, w2, b2, w3, b3, wa, ba, wc, bc, aggT, out_scores);
  // aggT (B,S,128) -> new_features (B,128,S)
  transpose_kernel<<<dim3(128 / 32, kS / 32, kB), dim3(32, 8, 1), 0, stream>>>(
      aggT, out_feat, kS, 128);
}